// Round 6
// baseline (282.811 us; speedup 1.0000x reference)
//
#include <hip/hip_runtime.h>

// CRF forward (log-partition minus gold score), B=2048, L=512, T=32.
// Bidirectional meet-in-the-middle with a SINGLE unified code path:
//   fwd:  alpha_t = f_t ∘ (E^T alpha_{t-1})      (dot-then-scale)
//   bwd:  gamma_t = f_t ∘ (E gamma_{t+1})        (same shape! gamma = f∘beta)
//   Z = sum_j (E^T alpha_m)[j] * gamma_{m+1}[j]
// Direction is pure runtime data: dt=±1, init index, and the LDS table
// s_tr[wv] (trans for fwd, trans^T for bwd) — used for BOTH the Eg register
// matrix (stride-1 loads, no bank conflicts) and the gold transition lookup
// (transposed-table trick makes the gold code identical in both dirs).
// R5 theory: two ~10KB unrolled paths thrashed shared instruction fetch
// (VALUBusy flat ~40% regardless of 2 vs 4 waves/SIMD). This version has ONE
// ~5KB hot loop shared by all waves: single chunk body + register copy for
// double-buffering, rolled tail.

constexpr int TT = 32;   // tags
constexpr int LL = 512;  // seq len

#define L2E  1.4426950408889634f
#define LN2f 0.6931471805599453f

template<int X>
__device__ __forceinline__ float swzxf(float v) {
  // lane ^ X within each 32-lane group (BitMode: and=0x1F, xor=X)
  return __int_as_float(__builtin_amdgcn_ds_swizzle(__float_as_int(v), (X << 10) | 0x1F));
}
__device__ __forceinline__ float rdlf(float v, int k) {
  return __int_as_float(__builtin_amdgcn_readlane(__float_as_int(v), k));
}
__device__ __forceinline__ int rdli(int v, int k) {
  return __builtin_amdgcn_readlane(v, k);
}

__global__ __launch_bounds__(128, 4) void crf_fwd(
    const float* __restrict__ emit, const float* __restrict__ trans,
    const int* __restrict__ tags, const int* __restrict__ lengths,
    float* __restrict__ out, int B)
{
  __shared__ float s_tr[2][TT * TT];   // [0] = trans, [1] = trans^T
  __shared__ float s_vec[2][TT];
  __shared__ float s_scl[2][2];

  {
#pragma unroll
    for (int k = 0; k < 8; ++k) {
      int idx = threadIdx.x + 128 * k;   // 0..1023
      float v = trans[idx];
      int rI = idx >> 5, cI = idx & 31;
      s_tr[0][idx] = v;
      s_tr[1][(cI << 5) | rI] = v;       // scattered, one-time
    }
  }
  __syncthreads();

  const int j  = threadIdx.x & 31;   // tag index (wave halves duplicate)
  const int ln = threadIdx.x & 63;   // lane in wave
  const int wv = threadIdx.x >> 6;   // 0 = forward (alpha), 1 = backward (gamma)
  const int b  = blockIdx.x;

  const float* tb = s_tr[wv];        // Eg source AND gold table (see header)

  // Eg[i]: fwd = E[i][j] (col j of E); bwd = E[j][i] = exp(transT[i][j]).
  // Both are tb[i*32+j]: stride-1, conflict-free.
  float Eg[TT];
#pragma unroll
  for (int i = 0; i < TT; ++i)
    Eg[i] = __builtin_amdgcn_exp2f(tb[i * TT + j] * L2E);
#pragma unroll
  for (int i = 0; i < TT; ++i) asm volatile("" : "+v"(Eg[i]));

  const int len = lengths[b];        // wave-uniform
  const int m   = (len - 1) >> 1;    // meet point
  const float* erow = emit + (size_t)b * (LL * TT);
  const int*   trow = tags + (size_t)b * LL;

  int ns, dt, tinit;
  if (wv == 0) { ns = m;                      dt =  1; tinit = 0;       }
  else         { ns = len - 2 - m; if (ns < 0) ns = 0; dt = -1; tinit = len - 1; }

  float a, gacc, LS = 0.f;
  if (wv == 1 && len < 2) { a = 1.f; gacc = 0.f; }   // gamma undefined; Z = sum(alpha_0)
  else {
    float e0 = erow[tinit * TT + j];
    int   t0 = trow[tinit];
    a    = __builtin_amdgcn_exp2f(e0 * L2E);   // alpha_0  /  gamma_{len-1} = f_{len-1}
    gacc = (j == t0) ? e0 : 0.f;               // emit gold at the init position
  }

  auto dot = [&](float x) -> float {           // 32 readlane + 32 fma (4 chains)
    float c0 = 0.f, c1 = 0.f, c2 = 0.f, c3 = 0.f;
#pragma unroll
    for (int q = 0; q < 8; ++q) {
      c0 = fmaf(rdlf(x, 4 * q + 0), Eg[4 * q + 0], c0);
      c1 = fmaf(rdlf(x, 4 * q + 1), Eg[4 * q + 1], c1);
      c2 = fmaf(rdlf(x, 4 * q + 2), Eg[4 * q + 2], c2);
      c3 = fmaf(rdlf(x, 4 * q + 3), Eg[4 * q + 3], c3);
    }
    return (c0 + c1) + (c2 + c3);
  };
  auto renorm = [&]() {                        // logz-invariant rescale
    float mt = fmaxf(a, 1e-30f);
    float mm = __int_as_float(__builtin_amdgcn_readfirstlane(__float_as_int(mt)));
    a *= __builtin_amdgcn_rcpf(mm);
    LS += __builtin_amdgcn_logf(mm);           // v_log_f32 = log2
  };
  auto clampi = [](int t) -> int { t = t > 0 ? t : 0; return t < LL ? t : LL - 1; };

  const int nf = ns >> 3;       // full 8-step chunks
  const int rr = ns & 7;        // rolled tail steps

  // double buffer: 8 emit floats + tag vector (lane q -> tags[tinit+dt*(s0+q)])
  float Ab[8], Bb[8];
  int tvA, tvB;
#pragma unroll
  for (int k = 0; k < 8; ++k) Ab[k] = erow[clampi(tinit + dt * (1 + k)) * TT + j];
  tvA = trow[clampi(tinit + dt * ln)];

  for (int c = 0; c < nf; ++c) {
    const int s0n = (c + 1) << 3;
    // prefetch next chunk
#pragma unroll
    for (int k = 0; k < 8; ++k)
      Bb[k] = erow[clampi(tinit + dt * (1 + s0n + k)) * TT + j];
    tvB = trow[clampi(tinit + dt * (s0n + ln))];

    // gold pre-work: step k uses gk (table row) and g{k+1} (attach lane).
    // fwd: gk=tags[t-1]=pv, gk1=tags[t]=ma, tb=trans   -> trans[pv][ma]
    // bwd: gk=tags[t+1]=nx, gk1=tags[t]=ma, tb=trans^T -> trans[ma][nx]
    int g0 = rdli(tvA, 0), g1 = rdli(tvA, 1), g2 = rdli(tvA, 2), g3 = rdli(tvA, 3),
        g4 = rdli(tvA, 4), g5 = rdli(tvA, 5), g6 = rdli(tvA, 6), g7 = rdli(tvA, 7),
        g8 = rdli(tvA, 8);
    float t0v = tb[(g0 << 5) + j], t1v = tb[(g1 << 5) + j];
    float t2v = tb[(g2 << 5) + j], t3v = tb[(g3 << 5) + j];
    float t4v = tb[(g4 << 5) + j], t5v = tb[(g5 << 5) + j];
    float t6v = tb[(g6 << 5) + j], t7v = tb[(g7 << 5) + j];
    float F0 = __builtin_amdgcn_exp2f(Ab[0] * L2E);
    float F1 = __builtin_amdgcn_exp2f(Ab[1] * L2E);
    float F2 = __builtin_amdgcn_exp2f(Ab[2] * L2E);
    float F3 = __builtin_amdgcn_exp2f(Ab[3] * L2E);
    float F4 = __builtin_amdgcn_exp2f(Ab[4] * L2E);
    float F5 = __builtin_amdgcn_exp2f(Ab[5] * L2E);
    float F6 = __builtin_amdgcn_exp2f(Ab[6] * L2E);
    float F7 = __builtin_amdgcn_exp2f(Ab[7] * L2E);

    a = dot(a) * F0;  gacc += (j == g1) ? (Ab[0] + t0v) : 0.f;
    a = dot(a) * F1;  gacc += (j == g2) ? (Ab[1] + t1v) : 0.f;
    a = dot(a) * F2;  gacc += (j == g3) ? (Ab[2] + t2v) : 0.f;
    a = dot(a) * F3;  gacc += (j == g4) ? (Ab[3] + t3v) : 0.f;
    renorm();
    a = dot(a) * F4;  gacc += (j == g5) ? (Ab[4] + t4v) : 0.f;
    a = dot(a) * F5;  gacc += (j == g6) ? (Ab[5] + t5v) : 0.f;
    a = dot(a) * F6;  gacc += (j == g7) ? (Ab[6] + t6v) : 0.f;
    a = dot(a) * F7;  gacc += (j == g8) ? (Ab[7] + t7v) : 0.f;
    renorm();

    // rotate buffers (register copy keeps ONE chunk body in the binary)
#pragma unroll
    for (int k = 0; k < 8; ++k) Ab[k] = Bb[k];
    tvA = tvB;
  }

  // rolled tail: <=7 steps, scalar tag loads (once per wave, latency ok)
  for (int k = 0; k < rr; ++k) {
    int s = (nf << 3) + k;
    int t = tinit + dt * (1 + s);
    float e  = erow[t * TT + j];
    int  ga  = trow[t - dt];       // fwd: pv = tags[t-1]; bwd: nx = tags[t+1]
    int  gb  = trow[t];            // ma = tags[t]
    float tr = tb[(ga << 5) + j];
    float F  = __builtin_amdgcn_exp2f(e * L2E);
    a = dot(a) * F;
    gacc += (j == gb) ? (e + tr) : 0.f;
    if ((k & 3) == 3) renorm();
  }

  // fwd: one extra dot-only step across the meet edge: abar = E^T alpha_m
  if (wv == 0 && len >= 2) a = dot(a);

  // per-wave gold reduction (both halves duplicated; group reduce suffices)
  float gs = gacc;
  gs += swzxf<1>(gs);  gs += swzxf<2>(gs);  gs += swzxf<4>(gs);
  gs += swzxf<8>(gs);  gs += swzxf<16>(gs);

  s_vec[wv][j] = a;                 // both halves write identical values
  if (ln == 0) { s_scl[wv][0] = gs; s_scl[wv][1] = LS; }
  __syncthreads();

  if (wv == 0) {
    float p = s_vec[0][j] * s_vec[1][j];
    p += swzxf<1>(p);  p += swzxf<2>(p);  p += swzxf<4>(p);
    p += swzxf<8>(p);  p += swzxf<16>(p);
    float logz = (__builtin_amdgcn_logf(p) + s_scl[0][1] + s_scl[1][1]) * LN2f;
    if (threadIdx.x == 0) {
      float gm = 0.f;
      if (len >= 2) {                // gold transition across the meet edge
        int tm = trow[m], tn = trow[m + 1];
        gm = s_tr[0][(tm << 5) + tn];
      }
      out[b] = logz - (s_scl[0][0] + s_scl[1][0] + gm);
    }
  }
}

extern "C" void kernel_launch(void* const* d_in, const int* in_sizes, int n_in,
                              void* d_out, int out_size, void* d_ws, size_t ws_size,
                              hipStream_t stream) {
  const float* emit    = (const float*)d_in[0];
  const float* trans   = (const float*)d_in[1];
  const int*   tags    = (const int*)d_in[2];
  const int*   lengths = (const int*)d_in[3];
  float*       out     = (float*)d_out;
  const int B = in_sizes[3];             // lengths is (B,)
  hipLaunchKernelGGL(crf_fwd, dim3(B), dim3(128), 0, stream,
                     emit, trans, tags, lengths, out, B);
}

// Round 8
// 270.830 us; speedup vs baseline: 1.0442x; 1.0442x over previous
//
#include <hip/hip_runtime.h>

// CRF forward (log-partition minus gold score), B=2048, L=512, T=32.
// Bidirectional meet-in-the-middle, single unified code path (see R6):
//   fwd:  alpha_t = f_t ∘ (E^T alpha_{t-1});  bwd: gamma_t = f_t ∘ (E gamma_{t+1})
//   Z = sum_j (E^T alpha_m)[j] * gamma_{m+1}[j]
// R7: force the Eg[32] register matrix to actually BE register-resident.
// Evidence from R2-R6: VGPR_Count 32-52 (vs ~70+ live values in source) with
// ZERO scratch traffic (WRITE_SIZE ~80 KB = output+memset; earlier "80MB
// spill" reading was a KB-vs-MB units error) -> the compiler REMATERIALIZES
// Eg from LDS (ds_read+mul+exp2) per use inside the hot loop. That re-creates
// the per-element LDS pattern on the critical chain and explains the flat
// ~40% VALUBusy / ~1000 cy/step across every structural change since R1.
// Fix: (a) amdgpu_waves_per_eu(1,4) -> VGPR budget 128 (launch needs only
// 4 waves/EU for full residency); (b) re-pin Eg with asm "+v" INSIDE the
// chunk loop -- an opaque def per iteration makes remat illegal, so Eg must
// stay in VGPRs (or spill to scratch, which WRITE_SIZE would expose).

constexpr int TT = 32;   // tags
constexpr int LL = 512;  // seq len

#define L2E  1.4426950408889634f
#define LN2f 0.6931471805599453f

template<int X>
__device__ __forceinline__ float swzxf(float v) {
  // lane ^ X within each 32-lane group (BitMode: and=0x1F, xor=X)
  return __int_as_float(__builtin_amdgcn_ds_swizzle(__float_as_int(v), (X << 10) | 0x1F));
}
__device__ __forceinline__ float rdlf(float v, int k) {
  return __int_as_float(__builtin_amdgcn_readlane(__float_as_int(v), k));
}
__device__ __forceinline__ int rdli(int v, int k) {
  return __builtin_amdgcn_readlane(v, k);
}

__global__ __launch_bounds__(128)
__attribute__((amdgpu_waves_per_eu(1, 4)))
void crf_fwd(
    const float* __restrict__ emit, const float* __restrict__ trans,
    const int* __restrict__ tags, const int* __restrict__ lengths,
    float* __restrict__ out, int B)
{
  __shared__ float s_tr[2][TT * TT];   // [0] = trans, [1] = trans^T
  __shared__ float s_vec[2][TT];
  __shared__ float s_scl[2][2];

  {
#pragma unroll
    for (int k = 0; k < 8; ++k) {
      int idx = threadIdx.x + 128 * k;   // 0..1023
      float v = trans[idx];
      int rI = idx >> 5, cI = idx & 31;
      s_tr[0][idx] = v;
      s_tr[1][(cI << 5) | rI] = v;       // scattered, one-time
    }
  }
  __syncthreads();

  const int j  = threadIdx.x & 31;   // tag index (wave halves duplicate)
  const int ln = threadIdx.x & 63;   // lane in wave
  const int wv = threadIdx.x >> 6;   // 0 = forward (alpha), 1 = backward (gamma)
  const int b  = blockIdx.x;

  const float* tb = s_tr[wv];        // Eg source AND gold table

  // Eg[i]: fwd = E[i][j] (col j of E); bwd = E[j][i] = exp(transT[i][j]).
  // Both are tb[i*32+j]: stride-1, conflict-free.
  float Eg[TT];
#pragma unroll
  for (int i = 0; i < TT; ++i)
    Eg[i] = __builtin_amdgcn_exp2f(tb[i * TT + j] * L2E);

  const int len = lengths[b];        // wave-uniform
  const int m   = (len - 1) >> 1;    // meet point
  const float* erow = emit + (size_t)b * (LL * TT);
  const int*   trow = tags + (size_t)b * LL;

  int ns, dt, tinit;
  if (wv == 0) { ns = m;                      dt =  1; tinit = 0;       }
  else         { ns = len - 2 - m; if (ns < 0) ns = 0; dt = -1; tinit = len - 1; }

  float a, gacc, LS = 0.f;
  if (wv == 1 && len < 2) { a = 1.f; gacc = 0.f; }   // gamma undefined; Z = sum(alpha_0)
  else {
    float e0 = erow[tinit * TT + j];
    int   t0 = trow[tinit];
    a    = __builtin_amdgcn_exp2f(e0 * L2E);   // alpha_0  /  gamma_{len-1} = f_{len-1}
    gacc = (j == t0) ? e0 : 0.f;               // emit gold at the init position
  }

  auto dot = [&](float x) -> float {           // 32 readlane + 32 fma (4 chains)
    float c0 = 0.f, c1 = 0.f, c2 = 0.f, c3 = 0.f;
#pragma unroll
    for (int q = 0; q < 8; ++q) {
      c0 = fmaf(rdlf(x, 4 * q + 0), Eg[4 * q + 0], c0);
      c1 = fmaf(rdlf(x, 4 * q + 1), Eg[4 * q + 1], c1);
      c2 = fmaf(rdlf(x, 4 * q + 2), Eg[4 * q + 2], c2);
      c3 = fmaf(rdlf(x, 4 * q + 3), Eg[4 * q + 3], c3);
    }
    return (c0 + c1) + (c2 + c3);
  };
  auto renorm = [&]() {                        // logz-invariant rescale
    float mt = fmaxf(a, 1e-30f);
    float mm = __int_as_float(__builtin_amdgcn_readfirstlane(__float_as_int(mt)));
    a *= __builtin_amdgcn_rcpf(mm);
    LS += __builtin_amdgcn_logf(mm);           // v_log_f32 = log2
  };
  auto clampi = [](int t) -> int { t = t > 0 ? t : 0; return t < LL ? t : LL - 1; };

  const int nf = ns >> 3;       // full 8-step chunks
  const int rr = ns & 7;        // rolled tail steps

  // double buffer: 8 emit floats + tag vector (lane q -> tags[tinit+dt*(s0+q)])
  float Ab[8], Bb[8];
  int tvA, tvB;
#pragma unroll
  for (int k = 0; k < 8; ++k) Ab[k] = erow[clampi(tinit + dt * (1 + k)) * TT + j];
  tvA = trow[clampi(tinit + dt * ln)];

  for (int c = 0; c < nf; ++c) {
    // Re-pin Eg EVERY iteration: opaque def -> remat from LDS is illegal,
    // values must remain VGPR-resident across the loop. Emits no code.
#pragma unroll
    for (int i = 0; i < TT; ++i) asm volatile("" : "+v"(Eg[i]));

    const int s0n = (c + 1) << 3;
    // prefetch next chunk
#pragma unroll
    for (int k = 0; k < 8; ++k)
      Bb[k] = erow[clampi(tinit + dt * (1 + s0n + k)) * TT + j];
    tvB = trow[clampi(tinit + dt * (s0n + ln))];

    // gold pre-work: step k uses gk (table row) and g{k+1} (attach lane).
    // fwd: gk=tags[t-1]=pv, gk1=tags[t]=ma, tb=trans   -> trans[pv][ma]
    // bwd: gk=tags[t+1]=nx, gk1=tags[t]=ma, tb=trans^T -> trans[ma][nx]
    int g0 = rdli(tvA, 0), g1 = rdli(tvA, 1), g2 = rdli(tvA, 2), g3 = rdli(tvA, 3),
        g4 = rdli(tvA, 4), g5 = rdli(tvA, 5), g6 = rdli(tvA, 6), g7 = rdli(tvA, 7),
        g8 = rdli(tvA, 8);
    float t0v = tb[(g0 << 5) + j], t1v = tb[(g1 << 5) + j];
    float t2v = tb[(g2 << 5) + j], t3v = tb[(g3 << 5) + j];
    float t4v = tb[(g4 << 5) + j], t5v = tb[(g5 << 5) + j];
    float t6v = tb[(g6 << 5) + j], t7v = tb[(g7 << 5) + j];
    float F0 = __builtin_amdgcn_exp2f(Ab[0] * L2E);
    float F1 = __builtin_amdgcn_exp2f(Ab[1] * L2E);
    float F2 = __builtin_amdgcn_exp2f(Ab[2] * L2E);
    float F3 = __builtin_amdgcn_exp2f(Ab[3] * L2E);
    float F4 = __builtin_amdgcn_exp2f(Ab[4] * L2E);
    float F5 = __builtin_amdgcn_exp2f(Ab[5] * L2E);
    float F6 = __builtin_amdgcn_exp2f(Ab[6] * L2E);
    float F7 = __builtin_amdgcn_exp2f(Ab[7] * L2E);

    a = dot(a) * F0;  gacc += (j == g1) ? (Ab[0] + t0v) : 0.f;
    a = dot(a) * F1;  gacc += (j == g2) ? (Ab[1] + t1v) : 0.f;
    a = dot(a) * F2;  gacc += (j == g3) ? (Ab[2] + t2v) : 0.f;
    a = dot(a) * F3;  gacc += (j == g4) ? (Ab[3] + t3v) : 0.f;
    renorm();
    a = dot(a) * F4;  gacc += (j == g5) ? (Ab[4] + t4v) : 0.f;
    a = dot(a) * F5;  gacc += (j == g6) ? (Ab[5] + t5v) : 0.f;
    a = dot(a) * F6;  gacc += (j == g7) ? (Ab[6] + t6v) : 0.f;
    a = dot(a) * F7;  gacc += (j == g8) ? (Ab[7] + t7v) : 0.f;
    renorm();

    // rotate buffers (register copy keeps ONE chunk body in the binary)
#pragma unroll
    for (int k = 0; k < 8; ++k) Ab[k] = Bb[k];
    tvA = tvB;
  }

  // rolled tail: <=7 steps, scalar tag loads (once per wave, latency ok)
  for (int k = 0; k < rr; ++k) {
    int s = (nf << 3) + k;
    int t = tinit + dt * (1 + s);
    float e  = erow[t * TT + j];
    int  ga  = trow[t - dt];       // fwd: pv = tags[t-1]; bwd: nx = tags[t+1]
    int  gb  = trow[t];            // ma = tags[t]
    float tr = tb[(ga << 5) + j];
    float F  = __builtin_amdgcn_exp2f(e * L2E);
    a = dot(a) * F;
    gacc += (j == gb) ? (e + tr) : 0.f;
    if ((k & 3) == 3) renorm();
  }

  // fwd: one extra dot-only step across the meet edge: abar = E^T alpha_m
  if (wv == 0 && len >= 2) a = dot(a);

  // per-wave gold reduction (both halves duplicated; group reduce suffices)
  float gs = gacc;
  gs += swzxf<1>(gs);  gs += swzxf<2>(gs);  gs += swzxf<4>(gs);
  gs += swzxf<8>(gs);  gs += swzxf<16>(gs);

  s_vec[wv][j] = a;                 // both halves write identical values
  if (ln == 0) { s_scl[wv][0] = gs; s_scl[wv][1] = LS; }
  __syncthreads();

  if (wv == 0) {
    float p = s_vec[0][j] * s_vec[1][j];
    p += swzxf<1>(p);  p += swzxf<2>(p);  p += swzxf<4>(p);
    p += swzxf<8>(p);  p += swzxf<16>(p);
    float logz = (__builtin_amdgcn_logf(p) + s_scl[0][1] + s_scl[1][1]) * LN2f;
    if (threadIdx.x == 0) {
      float gm = 0.f;
      if (len >= 2) {                // gold transition across the meet edge
        int tm = trow[m], tn = trow[m + 1];
        gm = s_tr[0][(tm << 5) + tn];
      }
      out[b] = logz - (s_scl[0][0] + s_scl[1][0] + gm);
    }
  }
}

extern "C" void kernel_launch(void* const* d_in, const int* in_sizes, int n_in,
                              void* d_out, int out_size, void* d_ws, size_t ws_size,
                              hipStream_t stream) {
  const float* emit    = (const float*)d_in[0];
  const float* trans   = (const float*)d_in[1];
  const int*   tags    = (const int*)d_in[2];
  const int*   lengths = (const int*)d_in[3];
  float*       out     = (float*)d_out;
  const int B = in_sizes[3];             // lengths is (B,)
  hipLaunchKernelGGL(crf_fwd, dim3(B), dim3(128), 0, stream,
                     emit, trans, tags, lengths, out, B);
}